// Round 2
// baseline (11751.251 us; speedup 1.0000x reference)
//
#include <hip/hip_runtime.h>
#include <stdint.h>

#define T_STEPS 1024
#define BATCH   64
#define DIN     256
#define HDIM    512
#define G4      2048

// ---- workspace layout (bytes) ----
#define OFF_CNT   0                            // 4 ints, stride 64 B
#define OFF_FLAG  512                          // 4 ints, stride 64 B
#define OFF_BIAS  4096                         // 2048 f32 (b_ih + b_hh)
#define OFF_WHH   16384                        // 2048*512 bf16
#define OFF_WIH   (16384 + G4*HDIM*2)          // 2048*256 bf16
#define OFF_H     (OFF_WIH + G4*DIN*2)         // 2*64*512 bf16 (double buffer, 128 KB)
#define OFF_XT    (OFF_H + 2*BATCH*HDIM*2)     // 1024*64*256 bf16
// total ≈ 36.9 MB

typedef __attribute__((ext_vector_type(8))) short bf16x8;
typedef __attribute__((ext_vector_type(4))) float f32x4;

__device__ __forceinline__ unsigned short f2bf(float f) {
  union { float f; unsigned u; } v; v.f = f;
  unsigned r = v.u + 0x7FFF + ((v.u >> 16) & 1);   // round-nearest-even
  return (unsigned short)(r >> 16);
}
__device__ __forceinline__ float sigm(float x)   { return 1.0f / (1.0f + __expf(-x)); }
__device__ __forceinline__ float tanh_f(float x) { return 2.0f / (1.0f + __expf(-2.0f * x)) - 1.0f; }

// ---- zero barrier state + h double-buffer (every launch: determinism) ----
__global__ void k_init(unsigned char* ws) {
  int tid = blockIdx.x * blockDim.x + threadIdx.x;
  unsigned* w32 = (unsigned*)ws;
  if (tid < 256) w32[tid] = 0;                       // cnt + flag region (1 KB)
  unsigned* h32 = (unsigned*)(ws + OFF_H);
  int n = 2 * BATCH * HDIM * 2 / 4;                  // 32768 dwords
  for (int i = tid; i < n; i += gridDim.x * blockDim.x) h32[i] = 0;
}

// ---- convert weights/bias/x to packed bf16 ----
__global__ void k_pack(const float* __restrict__ W_ih, const float* __restrict__ W_hh,
                       const float* __restrict__ b_ih, const float* __restrict__ b_hh,
                       const float* __restrict__ x, unsigned char* ws) {
  unsigned short* whh = (unsigned short*)(ws + OFF_WHH);
  unsigned short* wih = (unsigned short*)(ws + OFF_WIH);
  float* bias = (float*)(ws + OFF_BIAS);
  unsigned short* xt = (unsigned short*)(ws + OFF_XT);
  int tid = blockIdx.x * blockDim.x + threadIdx.x;
  int np = gridDim.x * blockDim.x;
  for (int i = tid; i < G4 * HDIM; i += np) whh[i] = f2bf(W_hh[i]);
  for (int i = tid; i < G4 * DIN;  i += np) wih[i] = f2bf(W_ih[i]);
  for (int i = tid; i < G4;        i += np) bias[i] = b_ih[i] + b_hh[i];
  for (int i = tid; i < T_STEPS * BATCH * DIN; i += np) {
    int t = i >> 14;                 // 64*256 = 2^14 per timestep
    int b = (i >> 8) & 63;
    int d = i & 255;
    xt[i] = f2bf(x[((b << 10) + t) * 256 + d]);   // x[b][t][d] -> xT[t][b][d]
  }
}

// ---- persistent LSTM kernel ----
// grid 256 WGs x 256 thr. WG=(bt 0..3, jt 0..63): 16 batches x (8 j * 4 gates).
__global__ __launch_bounds__(256, 2) void k_lstm(unsigned char* ws, float* __restrict__ out) {
  __shared__ __attribute__((aligned(16))) unsigned short A_s[16 * 776];    // [16][768+8] bf16 (gates f32 aliased at base)
  __shared__ __attribute__((aligned(16))) unsigned short Whh_s[32 * 520];  // [32][512+8]
  __shared__ __attribute__((aligned(16))) unsigned short Wih_s[32 * 264];  // [32][256+8]

  const int tid = threadIdx.x;
  const int wg  = blockIdx.x;
  const int bt  = wg >> 6;     // batch-group 0..3 (16 batches each)
  const int jt  = wg & 63;     // j-tile 0..63 (8 j each)

  const unsigned short* whh_g = (const unsigned short*)(ws + OFF_WHH);
  const unsigned short* wih_g = (const unsigned short*)(ws + OFF_WIH);
  const float*          bias_g = (const float*)(ws + OFF_BIAS);
  const unsigned short* xt_g  = (const unsigned short*)(ws + OFF_XT);
  unsigned*            hbuf32 = (unsigned*)(ws + OFF_H);            // [2][64][256] u32
  unsigned long long*  hbuf64 = (unsigned long long*)(ws + OFF_H);  // [2][64][128] u64
  int* cnt  = (int*)(ws + OFF_CNT);
  int* flag = (int*)(ws + OFF_FLAG);

  // --- preload W slices into LDS (row rl = gate-col n: grow = (n>>3)*512 + jt*8 + (n&7)) ---
  {
    int w = tid;                       // 256 chunks: 32 rows x 8 parts of 64 bf16
    int rl = w >> 3, part = w & 7;
    int grow = (rl >> 3) * 512 + jt * 8 + (rl & 7);
    const unsigned short* src = whh_g + grow * 512 + part * 64;
    unsigned short* dst = Whh_s + rl * 520 + part * 64;
    #pragma unroll
    for (int i = 0; i < 8; ++i) *(bf16x8*)(dst + i * 8) = *(const bf16x8*)(src + i * 8);
  }
  if (tid < 128) {                     // 128 chunks: 32 rows x 4 parts of 64 bf16
    int rl = tid >> 2, part = tid & 3;
    int grow = (rl >> 3) * 512 + jt * 8 + (rl & 7);
    const unsigned short* src = wih_g + grow * 256 + part * 64;
    unsigned short* dst = Wih_s + rl * 264 + part * 64;
    #pragma unroll
    for (int i = 0; i < 8; ++i) *(bf16x8*)(dst + i * 8) = *(const bf16x8*)(src + i * 8);
  }

  // --- updater threads (tid<64): 16 batches x 8 j, 2 j each; c lives in regs ---
  float biasr[2][4];
  float c_reg[2] = {0.f, 0.f};
  int ub = 0, j2 = 0;
  if (tid < 64) {
    ub = tid >> 2;           // local batch 0..15
    j2 = (tid & 3) * 2;      // local j 0,2,4,6
    #pragma unroll
    for (int e = 0; e < 2; ++e)
      #pragma unroll
      for (int gt = 0; gt < 4; ++gt)
        biasr[e][gt] = bias_g[gt * 512 + jt * 8 + j2 + e];
  }

  const int lane  = tid & 63, wave = tid >> 6;
  const int ntile = wave & 1;          // which 16-col MFMA tile
  const int kh    = wave >> 1;         // K half (12 kk-steps each)
  const int arow  = lane & 15;
  const int kg    = (lane >> 4) * 8;
  const int rl    = arow + ntile * 16;
  float* gl = (float*)A_s;             // gates [2 kh][16 m][32 n] f32, aliased

  __syncthreads();

  for (int t = 0; t < T_STEPS; ++t) {
    const int cur = t & 1, nxt = cur ^ 1;

    // --- stage A = [h(512) | x(256)] bf16 for 16 batches into LDS ---
    {
      int m = tid >> 4, ci = tid & 15;
      // h row = 512 bf16 = 1024 B = 128 u64; 16 threads x 8 u64 each
      const unsigned long long* hsrc = hbuf64 + (size_t)cur * (64 * 128) + (bt * 16 + m) * 128;
      unsigned long long* arow64 = (unsigned long long*)(A_s + m * 776);
      #pragma unroll
      for (int q = 0; q < 8; ++q) {
        int idx = ci + 16 * q;
        unsigned long long v = __hip_atomic_load(hsrc + idx, __ATOMIC_RELAXED, __HIP_MEMORY_SCOPE_AGENT);
        arow64[idx] = v;
      }
      const unsigned short* xsrc = xt_g + ((size_t)t * 64 + bt * 16 + m) * 256;
      #pragma unroll
      for (int q = 0; q < 2; ++q) {
        int c16 = ci + 16 * q;
        *(bf16x8*)(A_s + m * 776 + 512 + c16 * 8) = *(const bf16x8*)(xsrc + c16 * 8);
      }
    }
    __syncthreads();

    // --- K loop: 12 MFMAs per wave (16x16x32 bf16) ---
    f32x4 acc = {0.f, 0.f, 0.f, 0.f};
    #pragma unroll
    for (int u = 0; u < 12; ++u) {
      int kk = kh * 12 + u;
      bf16x8 a = *(const bf16x8*)(A_s + arow * 776 + kk * 32 + kg);
      bf16x8 b;
      if (kk < 16) b = *(const bf16x8*)(Whh_s + rl * 520 + kk * 32 + kg);
      else         b = *(const bf16x8*)(Wih_s + rl * 264 + (kk - 16) * 32 + kg);
      acc = __builtin_amdgcn_mfma_f32_16x16x32_bf16(a, b, acc, 0, 0, 0);
    }
    __syncthreads();   // all waves done reading A_s before gates alias-write

    #pragma unroll
    for (int r = 0; r < 4; ++r) {
      int m = (lane >> 4) * 4 + r;                // C/D layout: row=(lane>>4)*4+reg
      int n = ntile * 16 + (lane & 15);           //             col=lane&15
      gl[(kh * 16 + m) * 32 + n] = acc[r];
    }
    __syncthreads();

    // --- elementwise LSTM update (threads 0..63) ---
    if (tid < 64) {
      float hv[2], ov[2];
      #pragma unroll
      for (int e = 0; e < 2; ++e) {
        int jl = j2 + e;
        float gi = gl[(ub) * 32 +      jl] + gl[(16 + ub) * 32 +      jl] + biasr[e][0];
        float gf = gl[(ub) * 32 +  8 + jl] + gl[(16 + ub) * 32 +  8 + jl] + biasr[e][1];
        float gg = gl[(ub) * 32 + 16 + jl] + gl[(16 + ub) * 32 + 16 + jl] + biasr[e][2];
        float go = gl[(ub) * 32 + 24 + jl] + gl[(16 + ub) * 32 + 24 + jl] + biasr[e][3];
        float cv = sigm(gf) * c_reg[e] + sigm(gi) * tanh_f(gg);
        c_reg[e] = cv;
        float h = sigm(go) * tanh_f(cv);
        hv[e] = h; ov[e] = sigm(h);
      }
      int bglob = bt * 16 + ub;
      int jg = jt * 8 + j2;
      unsigned hp = (unsigned)f2bf(hv[0]) | ((unsigned)f2bf(hv[1]) << 16);
      __hip_atomic_store(hbuf32 + (size_t)nxt * (64 * 256) + bglob * 256 + (jg >> 1), hp,
                         __ATOMIC_RELAXED, __HIP_MEMORY_SCOPE_AGENT);
      float2 o2 = make_float2(ov[0], ov[1]);
      *(float2*)(out + ((size_t)t * 64 + bglob) * 512 + jg) = o2;
    }

    // --- group barrier (64 WGs sharing bt); h writes released to L3 ---
    if (t + 1 < T_STEPS) {
      __syncthreads();   // all threads' h stores issued before tid0's release-RMW
      if (tid == 0) {
        int v = __hip_atomic_fetch_add(cnt + bt * 16, 1, __ATOMIC_RELEASE, __HIP_MEMORY_SCOPE_AGENT);
        if (v == 64 * (t + 1) - 1)
          __hip_atomic_store(flag + bt * 16, t + 1, __ATOMIC_RELEASE, __HIP_MEMORY_SCOPE_AGENT);
        while (__hip_atomic_load(flag + bt * 16, __ATOMIC_ACQUIRE, __HIP_MEMORY_SCOPE_AGENT) < t + 1)
          __builtin_amdgcn_s_sleep(2);
        asm volatile("" ::: "memory");
      }
      __syncthreads();
    }
  }
}

extern "C" void kernel_launch(void* const* d_in, const int* in_sizes, int n_in,
                              void* d_out, int out_size, void* d_ws, size_t ws_size,
                              hipStream_t stream) {
  const float* x    = (const float*)d_in[0];
  const float* W_ih = (const float*)d_in[1];
  const float* W_hh = (const float*)d_in[2];
  const float* b_ih = (const float*)d_in[3];
  const float* b_hh = (const float*)d_in[4];
  float* out = (float*)d_out;
  unsigned char* ws = (unsigned char*)d_ws;

  hipLaunchKernelGGL(k_init, dim3(64),   dim3(256), 0, stream, ws);
  hipLaunchKernelGGL(k_pack, dim3(2048), dim3(256), 0, stream, W_ih, W_hh, b_ih, b_hh, x, ws);
  hipLaunchKernelGGL(k_lstm, dim3(256),  dim3(256), 0, stream, ws, out);
}

// Round 3
// 5801.601 us; speedup vs baseline: 2.0255x; 2.0255x over previous
//
#include <hip/hip_runtime.h>
#include <stdint.h>

#define T_STEPS 1024
#define BATCH   64
#define DIN     256
#define HDIM    512
#define G4      2048

// ---- workspace layout (bytes) ----
#define OFF_TAG   0                            // 256 ints: per-WG arrival tag
#define OFF_BIAS  4096                         // 2048 f32 (b_ih + b_hh)
#define OFF_WHH   16384                        // 2048*512 bf16
#define OFF_WIH   (16384 + G4*HDIM*2)          // 2048*256 bf16
#define OFF_H     (OFF_WIH + G4*DIN*2)         // 2*64*512 bf16 (double buffer)
#define OFF_XT    (OFF_H + 2*BATCH*HDIM*2)     // 1024*64*256 bf16

typedef __attribute__((ext_vector_type(8))) short bf16x8;
typedef __attribute__((ext_vector_type(4))) float f32x4;

__device__ __forceinline__ unsigned short f2bf(float f) {
  union { float f; unsigned u; } v; v.f = f;
  unsigned r = v.u + 0x7FFF + ((v.u >> 16) & 1);
  return (unsigned short)(r >> 16);
}
__device__ __forceinline__ float bf2f(unsigned short u) {
  union { unsigned u; float f; } v; v.u = ((unsigned)u) << 16; return v.f;
}
__device__ __forceinline__ float sigm(float x)   { return 1.0f / (1.0f + __expf(-x)); }
__device__ __forceinline__ float tanh_f(float x) { return 2.0f / (1.0f + __expf(-2.0f * x)) - 1.0f; }

__global__ void k_init(unsigned char* ws) {
  int tid = blockIdx.x * blockDim.x + threadIdx.x;
  unsigned* w32 = (unsigned*)ws;
  if (tid < 256) w32[tid] = 0;                       // tags
  unsigned* h32 = (unsigned*)(ws + OFF_H);
  int n = 2 * BATCH * HDIM * 2 / 4;
  for (int i = tid; i < n; i += gridDim.x * blockDim.x) h32[i] = 0;
}

__global__ void k_pack(const float* __restrict__ W_ih, const float* __restrict__ W_hh,
                       const float* __restrict__ b_ih, const float* __restrict__ b_hh,
                       const float* __restrict__ x, unsigned char* ws) {
  unsigned short* whh = (unsigned short*)(ws + OFF_WHH);
  unsigned short* wih = (unsigned short*)(ws + OFF_WIH);
  float* bias = (float*)(ws + OFF_BIAS);
  unsigned short* xt = (unsigned short*)(ws + OFF_XT);
  int tid = blockIdx.x * blockDim.x + threadIdx.x;
  int np = gridDim.x * blockDim.x;
  for (int i = tid; i < G4 * HDIM; i += np) whh[i] = f2bf(W_hh[i]);
  for (int i = tid; i < G4 * DIN;  i += np) wih[i] = f2bf(W_ih[i]);
  for (int i = tid; i < G4;        i += np) bias[i] = b_ih[i] + b_hh[i];
  for (int i = tid; i < T_STEPS * BATCH * DIN; i += np) {
    int t = i >> 14;
    int b = (i >> 8) & 63;
    int d = i & 255;
    xt[i] = f2bf(x[((b << 10) + t) * 256 + d]);
  }
}

// grid 256 WGs x 256 thr. WG=(bt 0..3, jt 0..63): 16 batches x (8 j * 4 gates).
// Per-row LDS A layout: h[512] | x[256] | pad -> stride 776 shorts.
__global__ __launch_bounds__(256, 1) void k_lstm(unsigned char* ws, float* __restrict__ out) {
  __shared__ __attribute__((aligned(16))) unsigned short A_s[16 * 776];
  __shared__ __attribute__((aligned(16))) unsigned short Whh_s[32 * 520];
  __shared__ __attribute__((aligned(16))) unsigned short Wih_s[32 * 264];
  __shared__ __attribute__((aligned(16))) float gl[2 * 16 * 32];

  const int tid = threadIdx.x;
  const int wg  = blockIdx.x;
  const int bt  = wg >> 6;
  const int jt  = wg & 63;

  const unsigned short* whh_g = (const unsigned short*)(ws + OFF_WHH);
  const unsigned short* wih_g = (const unsigned short*)(ws + OFF_WIH);
  const float*          bias_g = (const float*)(ws + OFF_BIAS);
  const unsigned short* xt_g  = (const unsigned short*)(ws + OFF_XT);
  unsigned*            hbuf32 = (unsigned*)(ws + OFF_H);            // [2][64][256] u32
  unsigned long long*  hbuf64 = (unsigned long long*)(ws + OFF_H);  // [2][64][128] u64
  unsigned* tag = (unsigned*)(ws + OFF_TAG);                        // [4][64]

  // --- preload W slices into LDS (row rl = gate-col n: grow = (n>>3)*512 + jt*8 + (n&7)) ---
  {
    int rl0 = tid >> 3, part = tid & 7;
    int grow = (rl0 >> 3) * 512 + jt * 8 + (rl0 & 7);
    const unsigned short* src = whh_g + grow * 512 + part * 64;
    unsigned short* dst = Whh_s + rl0 * 520 + part * 64;
    #pragma unroll
    for (int i = 0; i < 8; ++i) *(bf16x8*)(dst + i * 8) = *(const bf16x8*)(src + i * 8);
  }
  if (tid < 128) {
    int rl0 = tid >> 2, part = tid & 3;
    int grow = (rl0 >> 3) * 512 + jt * 8 + (rl0 & 7);
    const unsigned short* src = wih_g + grow * 256 + part * 64;
    unsigned short* dst = Wih_s + rl0 * 264 + part * 64;
    #pragma unroll
    for (int i = 0; i < 8; ++i) *(bf16x8*)(dst + i * 8) = *(const bf16x8*)(src + i * 8);
  }

  // --- updater setup (tid<64): 16 batches x 8 j, 2 j each; c in regs ---
  float biasr[2][4];
  float c_reg[2] = {0.f, 0.f};
  int ub = 0, j2 = 0;
  if (tid < 64) {
    ub = tid >> 2;
    j2 = (tid & 3) * 2;
    #pragma unroll
    for (int e = 0; e < 2; ++e)
      #pragma unroll
      for (int gt = 0; gt < 4; ++gt)
        biasr[e][gt] = bias_g[gt * 512 + jt * 8 + j2 + e];
  }

  const int lane  = tid & 63, wave = tid >> 6;
  const int ntile = wave & 1;
  const int kh    = wave >> 1;
  const int arow  = lane & 15;
  const int kg    = (lane >> 4) * 8;
  const int rl    = arow + ntile * 16;

  // --- preamble: h(0)=0 in LDS; stage x(0); accX(0); stage x(1) ---
  {
    int m = tid >> 4, ci = tid & 15;
    unsigned long long* r64 = (unsigned long long*)(A_s + m * 776);
    #pragma unroll
    for (int q = 0; q < 8; ++q) r64[ci + 16 * q] = 0ULL;
    const unsigned short* x0 = xt_g + ((size_t)0 * 64 + bt * 16 + m) * 256;
    #pragma unroll
    for (int q = 0; q < 2; ++q) {
      int c16 = ci + 16 * q;
      *(bf16x8*)(A_s + m * 776 + 512 + c16 * 8) = *(const bf16x8*)(x0 + c16 * 8);
    }
  }
  __syncthreads();

  f32x4 accX = {0.f, 0.f, 0.f, 0.f};
  #pragma unroll
  for (int u = 0; u < 4; ++u) {
    int kx = kh * 4 + u;           // 0..7
    bf16x8 a = *(const bf16x8*)(A_s + arow * 776 + 512 + kx * 32 + kg);
    bf16x8 b = *(const bf16x8*)(Wih_s + rl * 264 + kx * 32 + kg);
    accX = __builtin_amdgcn_mfma_f32_16x16x32_bf16(a, b, accX, 0, 0, 0);
  }
  __syncthreads();   // all waves done reading x(0) before restage
  {
    int m = tid >> 4, ci = tid & 15;
    const unsigned short* x1 = xt_g + ((size_t)1 * 64 + bt * 16 + m) * 256;
    #pragma unroll
    for (int q = 0; q < 2; ++q) {
      int c16 = ci + 16 * q;
      *(bf16x8*)(A_s + m * 776 + 512 + c16 * 8) = *(const bf16x8*)(x1 + c16 * 8);
    }
  }
  __syncthreads();

  // --- main loop. Invariant at top of iter t: A_s-h = h(t), A_s-x = x(t+1),
  //     accX = x(t)-projection, hbuf[(t)&1] holds h(t) globally. ---
  for (int t = 0; t < T_STEPS; ++t) {
    // P3: acc = accX + h-part MFMAs
    f32x4 acc = accX;
    #pragma unroll
    for (int u = 0; u < 8; ++u) {
      int kk = kh * 8 + u;         // 0..15
      bf16x8 a = *(const bf16x8*)(A_s + arow * 776 + kk * 32 + kg);
      bf16x8 b = *(const bf16x8*)(Whh_s + rl * 520 + kk * 32 + kg);
      acc = __builtin_amdgcn_mfma_f32_16x16x32_bf16(a, b, acc, 0, 0, 0);
    }
    #pragma unroll
    for (int r = 0; r < 4; ++r) {
      int m = (lane >> 4) * 4 + r;              // C/D: row=(lane>>4)*4+reg
      int n = ntile * 16 + (lane & 15);         //      col=lane&15
      gl[(kh * 16 + m) * 32 + n] = acc[r];
    }
    // coalesced out(t-1) = sigm(h(t)) from staged LDS h
    if (t > 0 && tid < 128) {
      int ub2 = jt >> 2, colb = (jt & 3) * 128 + tid;
      float hv = bf2f(A_s[ub2 * 776 + colb]);
      out[((size_t)(t - 1) * 64 + bt * 16 + ub2) * 512 + colb] = sigm(hv);
    }
    __syncthreads();   // P4: gates visible

    // P5: update (wave0) -> h(t+1) store + tag; then x-MFMAs for accX(t+1)
    if (tid < 64) {
      float hv[2];
      #pragma unroll
      for (int e = 0; e < 2; ++e) {
        int jl = j2 + e;
        float gi = gl[ub * 32 +      jl] + gl[512 + ub * 32 +      jl] + biasr[e][0];
        float gf = gl[ub * 32 +  8 + jl] + gl[512 + ub * 32 +  8 + jl] + biasr[e][1];
        float gg = gl[ub * 32 + 16 + jl] + gl[512 + ub * 32 + 16 + jl] + biasr[e][2];
        float go = gl[ub * 32 + 24 + jl] + gl[512 + ub * 32 + 24 + jl] + biasr[e][3];
        float cv = sigm(gf) * c_reg[e] + sigm(gi) * tanh_f(gg);
        c_reg[e] = cv;
        hv[e] = sigm(go) * tanh_f(cv);
      }
      int bglob = bt * 16 + ub;
      unsigned hp = (unsigned)f2bf(hv[0]) | ((unsigned)f2bf(hv[1]) << 16);
      __hip_atomic_store(hbuf32 + (size_t)((t + 1) & 1) * (64 * 256) + bglob * 256 + jt * 4 + (j2 >> 1),
                         hp, __ATOMIC_RELAXED, __HIP_MEMORY_SCOPE_AGENT);
      asm volatile("s_waitcnt vmcnt(0)" ::: "memory");   // wave0's h stores at L3
      if (tid == 0)
        __hip_atomic_store(&tag[bt * 64 + jt], (unsigned)(t + 1),
                           __ATOMIC_RELAXED, __HIP_MEMORY_SCOPE_AGENT);
    }

    if (t + 1 < T_STEPS) {
      // overlap: x(t+1) projection while other WGs finish
      accX = (f32x4){0.f, 0.f, 0.f, 0.f};
      #pragma unroll
      for (int u = 0; u < 4; ++u) {
        int kx = kh * 4 + u;
        bf16x8 a = *(const bf16x8*)(A_s + arow * 776 + 512 + kx * 32 + kg);
        bf16x8 b = *(const bf16x8*)(Wih_s + rl * 264 + kx * 32 + kg);
        accX = __builtin_amdgcn_mfma_f32_16x16x32_bf16(a, b, accX, 0, 0, 0);
      }
      // P6: relaxed tag spin (wave0 polls all 64 group tags, coalesced 256B)
      if (wave == 0) {
        for (;;) {
          unsigned v = __hip_atomic_load(&tag[bt * 64 + lane],
                                         __ATOMIC_RELAXED, __HIP_MEMORY_SCOPE_AGENT);
          if (__all((int)v >= (int)(t + 1))) break;
        }
      }
      __syncthreads();
      // P1': stage h(t+1); stage x(t+2)
      {
        int m = tid >> 4, ci = tid & 15;
        const unsigned long long* hsrc =
            hbuf64 + (size_t)((t + 1) & 1) * (64 * 128) + (bt * 16 + m) * 128;
        unsigned long long* r64 = (unsigned long long*)(A_s + m * 776);
        #pragma unroll
        for (int q = 0; q < 8; ++q)
          r64[ci + 16 * q] = __hip_atomic_load(hsrc + ci + 16 * q,
                                               __ATOMIC_RELAXED, __HIP_MEMORY_SCOPE_AGENT);
        if (t + 2 < T_STEPS) {
          const unsigned short* xsrc = xt_g + ((size_t)(t + 2) * 64 + bt * 16 + m) * 256;
          #pragma unroll
          for (int q = 0; q < 2; ++q) {
            int c16 = ci + 16 * q;
            *(bf16x8*)(A_s + m * 776 + 512 + c16 * 8) = *(const bf16x8*)(xsrc + c16 * 8);
          }
        }
      }
      __syncthreads();   // P2'
    }
  }

  // --- epilogue: out(1023) = sigm(h(1024)); h(1024) lives in hbuf[0] ---
  if (wave == 0) {
    for (;;) {
      unsigned v = __hip_atomic_load(&tag[bt * 64 + lane],
                                     __ATOMIC_RELAXED, __HIP_MEMORY_SCOPE_AGENT);
      if (__all((int)v >= T_STEPS)) break;
    }
  }
  __syncthreads();
  if (tid < 64) {
    int ub2 = jt >> 2;
    int cp  = (jt & 3) * 64 + tid;     // u32 index 0..255 within row
    unsigned v = __hip_atomic_load(hbuf32 + (size_t)(bt * 16 + ub2) * 256 + cp,
                                   __ATOMIC_RELAXED, __HIP_MEMORY_SCOPE_AGENT);
    float2 o2 = make_float2(sigm(bf2f((unsigned short)(v & 0xFFFFu))),
                            sigm(bf2f((unsigned short)(v >> 16))));
    *(float2*)(out + ((size_t)(T_STEPS - 1) * 64 + bt * 16 + ub2) * 512 + cp * 2) = o2;
  }
}

extern "C" void kernel_launch(void* const* d_in, const int* in_sizes, int n_in,
                              void* d_out, int out_size, void* d_ws, size_t ws_size,
                              hipStream_t stream) {
  const float* x    = (const float*)d_in[0];
  const float* W_ih = (const float*)d_in[1];
  const float* W_hh = (const float*)d_in[2];
  const float* b_ih = (const float*)d_in[3];
  const float* b_hh = (const float*)d_in[4];
  float* out = (float*)d_out;
  unsigned char* ws = (unsigned char*)d_ws;

  hipLaunchKernelGGL(k_init, dim3(64),   dim3(256), 0, stream, ws);
  hipLaunchKernelGGL(k_pack, dim3(2048), dim3(256), 0, stream, W_ih, W_hh, b_ih, b_hh, x, ws);
  hipLaunchKernelGGL(k_lstm, dim3(256),  dim3(256), 0, stream, ws, out);
}

// Round 5
// 2335.403 us; speedup vs baseline: 5.0318x; 2.4842x over previous
//
#include <hip/hip_runtime.h>
#include <stdint.h>

#define T_STEPS 1024
#define BATCH   64
#define DIN     256
#define HDIM    512
#define G4      2048
#define NGRP    8        // groups = XCDs
#define GWG     32       // WGs per group
#define GB      8        // batches per group
#define NBUF    16       // h ring depth (defeats L1 reuse; WGs stay within 1 step)

// ---- workspace layout (bytes) ----
#define OFF_XCNT  0                            // 8 ints: per-XCD rank counters
#define OFF_ARR   128                          // 8 arrive counters, 128B apart
#define OFF_BIAS  4096                         // 2048 f32 (b_ih + b_hh)
#define OFF_WHH   16384                        // 2048*512 bf16 (2 MB)
#define OFF_WIH   (16384 + G4*HDIM*2)          // 2048*256 bf16 (1 MB)
#define OFF_H     (OFF_WIH + G4*DIN*2)         // [NGRP][NBUF][8][512] bf16 = 1 MB
// total ≈ 4.2 MB (well under proven ws capacity)

typedef __attribute__((ext_vector_type(8))) short bf16x8;
typedef __attribute__((ext_vector_type(4))) float f32x4;

__device__ __forceinline__ unsigned short f2bf(float f) {
  union { float f; unsigned u; } v; v.f = f;
  unsigned r = v.u + 0x7FFF + ((v.u >> 16) & 1);
  return (unsigned short)(r >> 16);
}
__device__ __forceinline__ float sigm(float x)   { return 1.0f / (1.0f + __expf(-x)); }
__device__ __forceinline__ float tanh_f(float x) { return 2.0f / (1.0f + __expf(-2.0f * x)) - 1.0f; }

__global__ void k_init(unsigned char* ws) {
  int tid = blockIdx.x * blockDim.x + threadIdx.x;
  unsigned* w32 = (unsigned*)ws;
  if (tid < 512) w32[tid] = 0;                 // rank + arrive counters
}

__global__ void k_pack(const float* __restrict__ W_ih, const float* __restrict__ W_hh,
                       const float* __restrict__ b_ih, const float* __restrict__ b_hh,
                       unsigned char* ws) {
  unsigned short* whh = (unsigned short*)(ws + OFF_WHH);
  unsigned short* wih = (unsigned short*)(ws + OFF_WIH);
  float* bias = (float*)(ws + OFF_BIAS);
  int tid = blockIdx.x * blockDim.x + threadIdx.x;
  int np = gridDim.x * blockDim.x;
  for (int i = tid; i < G4 * HDIM; i += np) whh[i] = f2bf(W_hh[i]);
  for (int i = tid; i < G4 * DIN;  i += np) wih[i] = f2bf(W_ih[i]);
  for (int i = tid; i < G4;        i += np) bias[i] = b_ih[i] + b_hh[i];
}

// stage x[t] for this group's 8 batches into A_s x-region (bf16), direct from fp32 input
__device__ __forceinline__ void stage_x(const float* __restrict__ x, unsigned short* A_s,
                                        int g, int m, int c, int tstep) {
  const float* xb = x + ((size_t)(g * GB + m) * 1024 + tstep) * 256 + c * 8;
  float4 f0 = *(const float4*)(xb);
  float4 f1 = *(const float4*)(xb + 4);
  union { bf16x8 v; unsigned short s[8]; } u;
  u.s[0] = f2bf(f0.x); u.s[1] = f2bf(f0.y); u.s[2] = f2bf(f0.z); u.s[3] = f2bf(f0.w);
  u.s[4] = f2bf(f1.x); u.s[5] = f2bf(f1.y); u.s[6] = f2bf(f1.z); u.s[7] = f2bf(f1.w);
  *(bf16x8*)(A_s + m * 776 + 512 + c * 8) = u.v;
}

// 512 WGs x 256 thr launched; 32 participants per XCD (group = physical XCD).
// WG covers 8 batches x 64 gate cols (4 gates x 16 j), K=768. Exchange is XCD-L2-local.
__global__ __launch_bounds__(256, 1) void k_lstm(unsigned char* ws,
                                                 const float* __restrict__ x,
                                                 float* __restrict__ out) {
  __shared__ __attribute__((aligned(16))) unsigned short A_s[16 * 776];   // [16][512h|256x|8pad]
  __shared__ __attribute__((aligned(16))) unsigned short Whh_s[64 * 520]; // [64 cols][512+8]
  __shared__ __attribute__((aligned(16))) unsigned short Wih_s[64 * 264]; // [64 cols][256+8]
  __shared__ __attribute__((aligned(16))) float gl[16 * 64];
  __shared__ int s_rank;

  const int tid = threadIdx.x;

  unsigned xcc;
  asm("s_getreg_b32 %0, hwreg(HW_REG_XCC_ID)" : "=s"(xcc));
  xcc &= 7;
  unsigned* xcnt = (unsigned*)(ws + OFF_XCNT);
  if (tid == 0)
    s_rank = (int)__hip_atomic_fetch_add(&xcnt[xcc], 1u, __ATOMIC_RELAXED, __HIP_MEMORY_SCOPE_AGENT);
  __syncthreads();
  const int rank = s_rank;
  if (rank >= GWG) return;                    // non-participant exits, frees CU

  const int g  = (int)xcc;
  const int jt = rank;                        // j-tile 0..31 (16 j each)

  const unsigned short* whh_g = (const unsigned short*)(ws + OFF_WHH);
  const unsigned short* wih_g = (const unsigned short*)(ws + OFF_WIH);
  const float*          bias_g = (const float*)(ws + OFF_BIAS);
  unsigned short*       hring = (unsigned short*)(ws + OFF_H) + (size_t)g * (NBUF * GB * HDIM);
  unsigned* arrive = (unsigned*)(ws + OFF_ARR + g * 128);

  // --- preload W slices: LDS row rl (0..63) = gate col; gate=rl>>4, jloc=rl&15 ---
  {
    int rl = tid >> 2, part = tid & 3;
    int grow = (rl >> 4) * 512 + jt * 16 + (rl & 15);
    const unsigned short* src = whh_g + grow * 512 + part * 128;
    unsigned short* dst = Whh_s + rl * 520 + part * 128;
    #pragma unroll
    for (int i = 0; i < 16; ++i) *(bf16x8*)(dst + i * 8) = *(const bf16x8*)(src + i * 8);
    const unsigned short* src2 = wih_g + grow * 256 + part * 64;
    unsigned short* dst2 = Wih_s + rl * 264 + part * 64;
    #pragma unroll
    for (int i = 0; i < 8; ++i) *(bf16x8*)(dst2 + i * 8) = *(const bf16x8*)(src2 + i * 8);
  }

  // --- zero A_s (h(0)=0; pad rows 8..15 stay zero forever) ---
  {
    unsigned* a32 = (unsigned*)A_s;
    for (int i = tid; i < 16 * 776 / 2; i += 256) a32[i] = 0;
  }

  float biasr[4];
  float c_reg = 0.f;
  const int ub = tid >> 4, jl = tid & 15;     // updater mapping (tid<128)
  if (tid < 128) {
    #pragma unroll
    for (int gt = 0; gt < 4; ++gt)
      biasr[gt] = bias_g[gt * 512 + jt * 16 + jl];
  }

  const int lane = tid & 63, wave = tid >> 6;  // wave = gate (i,f,g,o)
  const int arow = lane & 15;
  const int kg   = (lane >> 4) * 8;
  const int rl   = wave * 16 + (lane & 15);    // B row (gate col within WG)
  const int sm   = tid >> 5, sc = tid & 31;    // staging mapping: 8 rows x 32 thr

  __syncthreads();

  // --- preamble: stage x(0); accX(0); stage x(1) ---
  stage_x(x, A_s, g, sm, sc, 0);
  __syncthreads();
  f32x4 accX = {0.f, 0.f, 0.f, 0.f};
  #pragma unroll
  for (int kx = 0; kx < 8; ++kx) {
    bf16x8 a = *(const bf16x8*)(A_s + arow * 776 + 512 + kx * 32 + kg);
    bf16x8 b = *(const bf16x8*)(Wih_s + rl * 264 + kx * 32 + kg);
    accX = __builtin_amdgcn_mfma_f32_16x16x32_bf16(a, b, accX, 0, 0, 0);
  }
  __syncthreads();
  stage_x(x, A_s, g, sm, sc, 1);
  __syncthreads();

  // --- main loop. Top of iter t: A_s-h = h(t), A_s-x = x(t+1), accX = xproj(t). ---
  for (int t = 0; t < T_STEPS; ++t) {
    f32x4 acc = accX;
    #pragma unroll
    for (int kk = 0; kk < 16; ++kk) {
      bf16x8 a = *(const bf16x8*)(A_s + arow * 776 + kk * 32 + kg);
      bf16x8 b = *(const bf16x8*)(Whh_s + rl * 520 + kk * 32 + kg);
      acc = __builtin_amdgcn_mfma_f32_16x16x32_bf16(a, b, acc, 0, 0, 0);
    }
    #pragma unroll
    for (int r = 0; r < 4; ++r) {
      int m = (lane >> 4) * 4 + r;             // C/D: row=(lane>>4)*4+reg, col=lane&15
      gl[m * 64 + wave * 16 + (lane & 15)] = acc[r];
    }
    __syncthreads();

    // update (tid<128): gates -> c,h; h store to ring slot (t+1)&15 (plain, L2-local)
    float hv = 0.f;
    if (tid < 128) {
      float gi = gl[ub * 64 +      jl] + biasr[0];
      float gf = gl[ub * 64 + 16 + jl] + biasr[1];
      float gg = gl[ub * 64 + 32 + jl] + biasr[2];
      float go = gl[ub * 64 + 48 + jl] + biasr[3];
      float cv = sigm(gf) * c_reg + sigm(gi) * tanh_f(gg);
      c_reg = cv;
      hv = sigm(go) * tanh_f(cv);
      if (t + 1 < T_STEPS) {
        unsigned short* hd = hring + (size_t)((t + 1) & (NBUF - 1)) * (GB * HDIM);
        hd[ub * HDIM + jt * 16 + jl] = f2bf(hv);
        asm volatile("s_waitcnt vmcnt(0)" ::: "memory");   // h stores at L2
      }
    }
    __syncthreads();                            // all h stores drained

    if (tid == 0 && t + 1 < T_STEPS)
      __hip_atomic_fetch_add(arrive, 1u, __ATOMIC_RELAXED, __HIP_MEMORY_SCOPE_WORKGROUP);
    if (tid < 128)
      out[((size_t)t * 64 + g * GB + ub) * 512 + jt * 16 + jl] = sigm(hv);

    if (t + 1 < T_STEPS) {
      // overlap: x(t+1) projection while group finishes
      accX = (f32x4){0.f, 0.f, 0.f, 0.f};
      #pragma unroll
      for (int kx = 0; kx < 8; ++kx) {
        bf16x8 a = *(const bf16x8*)(A_s + arow * 776 + 512 + kx * 32 + kg);
        bf16x8 b = *(const bf16x8*)(Wih_s + rl * 264 + kx * 32 + kg);
        accX = __builtin_amdgcn_mfma_f32_16x16x32_bf16(a, b, accX, 0, 0, 0);
      }
      // poll: non-identity RMW (can't fold to load), executes at L2; count in low 31 bits
      if (tid == 0) {
        unsigned target = (unsigned)(GWG * (t + 1));
        int it = 0;
        for (;;) {
          unsigned v = __hip_atomic_fetch_or(arrive, 0x80000000u,
                                             __ATOMIC_RELAXED, __HIP_MEMORY_SCOPE_WORKGROUP);
          if ((v & 0x7FFFFFFFu) >= target) break;
          if (++it > (1 << 18)) break;         // hang insurance only
        }
      }
      __syncthreads();
      // stage h(t+1) from ring (fresh addresses -> plain loads safe) + x(t+2)
      {
        const unsigned short* hs = hring + (size_t)((t + 1) & (NBUF - 1)) * (GB * HDIM)
                                 + sm * HDIM + sc * 16;
        bf16x8 h0 = *(const bf16x8*)(hs);
        bf16x8 h1 = *(const bf16x8*)(hs + 8);
        *(bf16x8*)(A_s + sm * 776 + sc * 16)     = h0;
        *(bf16x8*)(A_s + sm * 776 + sc * 16 + 8) = h1;
        if (t + 2 < T_STEPS) stage_x(x, A_s, g, sm, sc, t + 2);
      }
      __syncthreads();
    }
  }
}

extern "C" void kernel_launch(void* const* d_in, const int* in_sizes, int n_in,
                              void* d_out, int out_size, void* d_ws, size_t ws_size,
                              hipStream_t stream) {
  const float* x    = (const float*)d_in[0];
  const float* W_ih = (const float*)d_in[1];
  const float* W_hh = (const float*)d_in[2];
  const float* b_ih = (const float*)d_in[3];
  const float* b_hh = (const float*)d_in[4];
  float* out = (float*)d_out;
  unsigned char* ws = (unsigned char*)d_ws;

  hipLaunchKernelGGL(k_init, dim3(2),    dim3(256), 0, stream, ws);
  hipLaunchKernelGGL(k_pack, dim3(1024), dim3(256), 0, stream, W_ih, W_hh, b_ih, b_hh, ws);
  hipLaunchKernelGGL(k_lstm, dim3(512),  dim3(256), 0, stream, ws, x, out);
}